// Round 1
// baseline (115.282 us; speedup 1.0000x reference)
//
#include <hip/hip_runtime.h>

// Problem constants
#define B_      4
#define CIN     128
#define COUT    128
#define KSZ     3
#define HSP     16
#define HW      256          // 16*16
#define WN      147456       // 128*128*9
#define WPK     1152         // per-co kernel elems = 128*9
#define ADIM    16

// ws float layout
#define WS_G     0            // g[0..127]
#define WS_G0    128
#define WS_S1    129
#define WS_S0    130
#define WS_BO    131
#define WS_A     132          // A[b][k], 4*7
#define WS_PART  160          // moment partials, 144 blocks * 6
#define NBLK_MOM 144

__device__ __forceinline__ float waveReduceSum(float v) {
    #pragma unroll
    for (int off = 32; off; off >>= 1) v += __shfl_down(v, off, 64);
    return v;
}

// 256-thread block sum, result broadcast to all threads. Safe to call repeatedly.
__device__ __forceinline__ float blockReduceSum256(float v, float* tmp4, int tid) {
    v = waveReduceSum(v);
    __syncthreads();                     // protect tmp4 from previous call's readers
    if ((tid & 63) == 0) tmp4[tid >> 6] = v;
    __syncthreads();
    return tmp4[0] + tmp4[1] + tmp4[2] + tmp4[3];
}

// K1: moments S1..S6 of wflat (per-block partials) + tiny projections (block 0)
__global__ __launch_bounds__(256) void k_moments(
        const float* __restrict__ w,
        const float* __restrict__ fcq,  const float* __restrict__ fcqb,
        const float* __restrict__ fck,
        const float* __restrict__ fcv,  const float* __restrict__ fcvb,
        const float* __restrict__ fco,  const float* __restrict__ fcob,
        float* __restrict__ ws) {
    __shared__ float tmp4[4];
    const int tid = threadIdx.x, blk = blockIdx.x;

    const float4 w4 = *reinterpret_cast<const float4*>(w + (size_t)(blk * 256 + tid) * 4);
    float m0 = 0.f, m1 = 0.f, m2 = 0.f, m3 = 0.f, m4 = 0.f, m5 = 0.f;
    float vals[4] = {w4.x, w4.y, w4.z, w4.w};
    #pragma unroll
    for (int i = 0; i < 4; ++i) {
        float v = vals[i], v2 = v * v, v3 = v2 * v;
        m0 += v; m1 += v2; m2 += v3; m3 += v2 * v2; m4 += v2 * v3; m5 += v3 * v3;
    }
    float ms[6] = {m0, m1, m2, m3, m4, m5};
    #pragma unroll
    for (int k = 0; k < 6; ++k) {
        float s = blockReduceSum256(ms[k], tmp4, tid);
        if (tid == 0) ws[WS_PART + blk * 6 + k] = s;
    }
    if (blk == 0) {
        if (tid < 128) {                 // g[c] = sum_a Wq[a,c] * fk[a]
            float s = 0.f;
            #pragma unroll
            for (int a = 0; a < ADIM; ++a) s += fcq[a * CIN + tid] * fck[a];
            ws[WS_G + tid] = s;
        } else if (tid == 128) {         // g0 = sum_a bq[a]*fk[a]
            float s = 0.f;
            for (int a = 0; a < ADIM; ++a) s += fcqb[a] * fck[a];
            ws[WS_G0] = s;
        } else if (tid == 129) {         // s1 = sum_a fv[a]*fo[a]
            float s = 0.f;
            for (int a = 0; a < ADIM; ++a) s += fcv[a] * fco[a];
            ws[WS_S1] = s;
        } else if (tid == 130) {         // s0 = sum_a bv[a]*fo[a]
            float s = 0.f;
            for (int a = 0; a < ADIM; ++a) s += fcvb[a] * fco[a];
            ws[WS_S0] = s;
        } else if (tid == 131) {
            ws[WS_BO] = fcob[0];
        }
    }
}

// K2: one block per batch b. alpha per (b,hw); Z via moment poly; A_k[b] reduction.
__global__ __launch_bounds__(256) void k_alpha(
        const float* __restrict__ x, float* __restrict__ ws) {
    __shared__ float tmp4[4];
    __shared__ float S[7];               // S[1..6]
    __shared__ float gl[128];
    __shared__ float g0s;
    const int tid = threadIdx.x, b = blockIdx.x;

    // reduce moment partials (144 blocks x 6)
    #pragma unroll
    for (int k = 0; k < 6; ++k) {
        float v = (tid < NBLK_MOM) ? ws[WS_PART + tid * 6 + k] : 0.f;
        float s = blockReduceSum256(v, tmp4, tid);
        if (tid == 0) S[k + 1] = s;
    }
    if (tid < 128) gl[tid] = ws[WS_G + tid];
    if (tid == 128) g0s = ws[WS_G0];
    __syncthreads();

    // alpha for query hw=tid of batch b: (g . x[b,:,hw] + g0) / sqrt(A=16)
    float dot = g0s;
    const float* xb = x + (size_t)b * CIN * HW + tid;
    #pragma unroll 8
    for (int c = 0; c < CIN; ++c) dot += xb[c * HW] * gl[c];
    const float alpha = dot * 0.25f;

    // Z(alpha) = WN + S1 a + S2 a^2/2 + ... + S6 a^6/720  (deg-6 Taylor, |a*w|<<1)
    float Z = S[6] * (1.f / 720.f);
    Z = Z * alpha + S[5] * (1.f / 120.f);
    Z = Z * alpha + S[4] * (1.f / 24.f);
    Z = Z * alpha + S[3] * (1.f / 6.f);
    Z = Z * alpha + S[2] * 0.5f;
    Z = Z * alpha + S[1];
    Z = Z * alpha + (float)WN;

    const float r = 1.0f / ((float)HW * Z);

    // A_k[b] = sum_q r_q * alpha_q^k / k!
    float t = r;
    const float invk[7] = {1.f, 1.f, 0.5f, 1.f / 3.f, 0.25f, 0.2f, 1.f / 6.f};
    #pragma unroll
    for (int k = 0; k < 7; ++k) {
        float s = blockReduceSum256(t, tmp4, tid);
        if (tid == 0) ws[WS_A + b * 7 + k] = s;
        t = t * alpha * invk[k + 1 > 6 ? 6 : k + 1];  // next term: * alpha / (k+1)
    }
}

// K3: one block per (b, co). Build masked kernel slice in LDS, then 3x3 conv.
#define CTILE 8
__global__ __launch_bounds__(256) void k_conv(
        const float* __restrict__ x, const float* __restrict__ w,
        const float* __restrict__ ws, const float* __restrict__ gamma,
        float* __restrict__ out) {
    __shared__ float mw[WPK];
    __shared__ float xp[CTILE][18][18];
    const int tid = threadIdx.x;
    const int blk = blockIdx.x;
    const int b = blk >> 7, co = blk & 127;

    const float A0 = ws[WS_A + b * 7 + 0], A1 = ws[WS_A + b * 7 + 1];
    const float A2 = ws[WS_A + b * 7 + 2], A3 = ws[WS_A + b * 7 + 3];
    const float A4 = ws[WS_A + b * 7 + 4], A5 = ws[WS_A + b * 7 + 5];
    const float A6 = ws[WS_A + b * 7 + 6];
    const float s1 = ws[WS_S1], s0 = ws[WS_S0], bo = ws[WS_BO];
    const float gam = gamma[0];

    // masked weights for this (b,co): mw = w + gam*(attnMean*(s1*w+s0)+bo)
    for (int i = tid; i < WPK; i += 256) {
        float wv = w[(size_t)co * WPK + i];
        float p = A6;
        p = p * wv + A5; p = p * wv + A4; p = p * wv + A3;
        p = p * wv + A2; p = p * wv + A1; p = p * wv + A0;   // attnMean(wv)
        mw[i] = wv + gam * (p * (s1 * wv + s0) + bo);
    }
    // zero halo (borders stay zero for all rounds; interior rewritten each round)
    {
        float* xpf = &xp[0][0][0];
        for (int i = tid; i < CTILE * 18 * 18; i += 256) xpf[i] = 0.f;
    }
    const int ox = tid & 15, oy = tid >> 4;
    float acc = 0.f;
    const float* xb = x + (size_t)b * CIN * HW;

    for (int c0 = 0; c0 < CIN; c0 += CTILE) {
        __syncthreads();                       // prev round reads done / zeros visible
        #pragma unroll
        for (int cc = 0; cc < CTILE; ++cc)
            xp[cc][oy + 1][ox + 1] = xb[(c0 + cc) * HW + tid];
        __syncthreads();                       // planes + mw visible
        #pragma unroll
        for (int cc = 0; cc < CTILE; ++cc) {
            const float* mwp = &mw[(c0 + cc) * 9];
            #pragma unroll
            for (int ky = 0; ky < 3; ++ky)
                #pragma unroll
                for (int kx = 0; kx < 3; ++kx)
                    acc += xp[cc][oy + ky][ox + kx] * mwp[ky * 3 + kx];
        }
    }
    out[(size_t)blk * HW + tid] = acc;
}

extern "C" void kernel_launch(void* const* d_in, const int* in_sizes, int n_in,
                              void* d_out, int out_size, void* d_ws, size_t ws_size,
                              hipStream_t stream) {
    const float* x    = (const float*)d_in[0];
    const float* wt   = (const float*)d_in[1];
    const float* fcq  = (const float*)d_in[2];
    const float* fcqb = (const float*)d_in[3];
    const float* fck  = (const float*)d_in[4];
    // d_in[5] = fc_k_b: cancels in softmax (constant shift over n) -- unused
    const float* fcv  = (const float*)d_in[6];
    const float* fcvb = (const float*)d_in[7];
    const float* fco  = (const float*)d_in[8];
    const float* fcob = (const float*)d_in[9];
    const float* gam  = (const float*)d_in[10];
    float* ws  = (float*)d_ws;
    float* out = (float*)d_out;

    hipLaunchKernelGGL(k_moments, dim3(NBLK_MOM), dim3(256), 0, stream,
                       wt, fcq, fcqb, fck, fcv, fcvb, fco, fcob, ws);
    hipLaunchKernelGGL(k_alpha, dim3(B_), dim3(256), 0, stream, x, ws);
    hipLaunchKernelGGL(k_conv, dim3(B_ * COUT), dim3(256), 0, stream,
                       x, wt, ws, gam, out);
}

// Round 2
// 107.379 us; speedup vs baseline: 1.0736x; 1.0736x over previous
//
#include <hip/hip_runtime.h>

// Problem constants
#define B_      4
#define CIN     128
#define COUT    128
#define HW      256          // 16*16
#define WN      147456       // 128*128*9
#define WPK     1152         // per-co kernel elems = 128*9
#define ADIM    16

// ws float layout (scalars)
#define WS_G     0            // g[0..127]
#define WS_G0    128
#define WS_S1    129
#define WS_S0    130
#define WS_BO    131
#define WS_A     132          // A[b][k], 4*7
#define WS_PART  160          // moment partials, 144 blocks * 6
#define NBLK_MOM 144
// ws byte layout (bf16 tensors)
#define MWT_OFF  4096                         // mwT[b][j][co][ci] bf16: 4*9*128*128
#define XT_OFF   (4096 + 4*9*128*128*2)       // xT[b][18][18][ci] bf16: 4*324*128

typedef __attribute__((ext_vector_type(8))) short bf16x8;
typedef __attribute__((ext_vector_type(4))) float f32x4;

__device__ __forceinline__ unsigned short f2bf(float f) {
    union { float f; unsigned int u; } v; v.f = f;
    unsigned int u = v.u;
    return (unsigned short)((u + 0x7FFFu + ((u >> 16) & 1u)) >> 16);  // RNE
}

__device__ __forceinline__ float waveReduceSum(float v) {
    #pragma unroll
    for (int off = 32; off; off >>= 1) v += __shfl_down(v, off, 64);
    return v;
}

// 256-thread block sum, broadcast. Safe to call repeatedly.
__device__ __forceinline__ float blockSum256(float v, float* tmp4, int tid) {
    v = waveReduceSum(v);
    __syncthreads();
    if ((tid & 63) == 0) tmp4[tid >> 6] = v;
    __syncthreads();
    return tmp4[0] + tmp4[1] + tmp4[2] + tmp4[3];
}

// 1024-thread block sum, broadcast.
__device__ __forceinline__ float blockSum1024(float v, float* tmp16, int tid) {
    v = waveReduceSum(v);
    __syncthreads();
    if ((tid & 63) == 0) tmp16[tid >> 6] = v;
    __syncthreads();
    float s = 0.f;
    #pragma unroll
    for (int i = 0; i < 16; ++i) s += tmp16[i];
    return s;
}

// K1: moments S1..S6 of wflat (per-block partials) + tiny projections (block 0)
__global__ __launch_bounds__(256) void k_moments(
        const float* __restrict__ w,
        const float* __restrict__ fcq,  const float* __restrict__ fcqb,
        const float* __restrict__ fck,
        const float* __restrict__ fcv,  const float* __restrict__ fcvb,
        const float* __restrict__ fco,  const float* __restrict__ fcob,
        float* __restrict__ ws) {
    __shared__ float tmp4[4];
    const int tid = threadIdx.x, blk = blockIdx.x;

    const float4 w4 = *reinterpret_cast<const float4*>(w + (size_t)(blk * 256 + tid) * 4);
    float m0 = 0.f, m1 = 0.f, m2 = 0.f, m3 = 0.f, m4 = 0.f, m5 = 0.f;
    float vals[4] = {w4.x, w4.y, w4.z, w4.w};
    #pragma unroll
    for (int i = 0; i < 4; ++i) {
        float v = vals[i], v2 = v * v, v3 = v2 * v;
        m0 += v; m1 += v2; m2 += v3; m3 += v2 * v2; m4 += v2 * v3; m5 += v3 * v3;
    }
    float ms[6] = {m0, m1, m2, m3, m4, m5};
    #pragma unroll
    for (int k = 0; k < 6; ++k) {
        float s = blockSum256(ms[k], tmp4, tid);
        if (tid == 0) ws[WS_PART + blk * 6 + k] = s;
    }
    if (blk == 0) {
        if (tid < 128) {                 // g[c] = sum_a Wq[a,c] * fk[a]
            float s = 0.f;
            #pragma unroll
            for (int a = 0; a < ADIM; ++a) s += fcq[a * CIN + tid] * fck[a];
            ws[WS_G + tid] = s;
        } else if (tid == 128) {
            float s = 0.f;
            for (int a = 0; a < ADIM; ++a) s += fcqb[a] * fck[a];
            ws[WS_G0] = s;
        } else if (tid == 129) {
            float s = 0.f;
            for (int a = 0; a < ADIM; ++a) s += fcv[a] * fco[a];
            ws[WS_S1] = s;
        } else if (tid == 130) {
            float s = 0.f;
            for (int a = 0; a < ADIM; ++a) s += fcvb[a] * fco[a];
            ws[WS_S0] = s;
        } else if (tid == 131) {
            ws[WS_BO] = fcob[0];
        }
    }
}

// K2: one block per batch. 1024 threads: (pixel p, ci-group cg) partial dots,
// then Z via moment poly and A_k[b] reductions.
__global__ __launch_bounds__(1024) void k_alpha(
        const float* __restrict__ x, float* __restrict__ ws) {
    __shared__ float tmp16[16];
    __shared__ float S[7];
    __shared__ float gl[128];
    __shared__ float g0s;
    __shared__ float psum[4][256];
    const int tid = threadIdx.x, b = blockIdx.x;
    const int p = tid & 255, cg = tid >> 8;

    // reduce moment partials (144 x 6)
    #pragma unroll
    for (int k = 0; k < 6; ++k) {
        float v = (tid < NBLK_MOM) ? ws[WS_PART + tid * 6 + k] : 0.f;
        float s = blockSum1024(v, tmp16, tid);
        if (tid == 0) S[k + 1] = s;
    }
    if (tid < 128) gl[tid] = ws[WS_G + tid];
    if (tid == 128) g0s = ws[WS_G0];
    __syncthreads();

    // partial dot over this thread's 32 channels (coalesced across lanes)
    float dot = 0.f;
    const float* xb = x + (size_t)b * CIN * HW + p;
    const int c0 = cg * 32;
    #pragma unroll 8
    for (int c = 0; c < 32; ++c) dot += xb[(c0 + c) * HW] * gl[c0 + c];
    psum[cg][p] = dot;
    __syncthreads();

    float alpha = 0.f, r = 0.f;
    if (cg == 0) {
        alpha = (psum[0][p] + psum[1][p] + psum[2][p] + psum[3][p] + g0s) * 0.25f;
        // Z(alpha): deg-6 Taylor via raw moments (|alpha*w| << 1)
        float Z = S[6] * (1.f / 720.f);
        Z = Z * alpha + S[5] * (1.f / 120.f);
        Z = Z * alpha + S[4] * (1.f / 24.f);
        Z = Z * alpha + S[3] * (1.f / 6.f);
        Z = Z * alpha + S[2] * 0.5f;
        Z = Z * alpha + S[1];
        Z = Z * alpha + (float)WN;
        r = 1.0f / ((float)HW * Z);
    }
    // A_k[b] = sum_q r_q * alpha_q^k / k!
    float t = r;
    const float invk[7] = {1.f, 1.f, 0.5f, 1.f / 3.f, 0.25f, 0.2f, 1.f / 6.f};
    #pragma unroll
    for (int k = 0; k < 7; ++k) {
        float s = blockSum1024(t, tmp16, tid);
        if (tid == 0) ws[WS_A + b * 7 + k] = s;
        t = t * alpha * invk[k + 1 > 6 ? 6 : k + 1];
    }
}

// K2.5a: masked weights -> bf16, transposed to [b][j][co][ci] (ci contiguous)
__global__ __launch_bounds__(256) void k_mask(
        const float* __restrict__ w, const float* __restrict__ ws,
        const float* __restrict__ gamma, unsigned short* __restrict__ mwT) {
    const int b = blockIdx.x >> 3, chunk = blockIdx.x & 7;
    const float A0 = ws[WS_A + b * 7 + 0], A1 = ws[WS_A + b * 7 + 1];
    const float A2 = ws[WS_A + b * 7 + 2], A3 = ws[WS_A + b * 7 + 3];
    const float A4 = ws[WS_A + b * 7 + 4], A5 = ws[WS_A + b * 7 + 5];
    const float A6 = ws[WS_A + b * 7 + 6];
    const float s1 = ws[WS_S1], s0 = ws[WS_S0], bo = ws[WS_BO];
    const float gam = gamma[0];

    const int end = chunk * 2048 + 2048;
    for (int i = chunk * 2048 + threadIdx.x; i < end; i += 256) {
        const int co = i >> 7, ci = i & 127;
        const float* wp = w + co * WPK + ci * 9;
        #pragma unroll
        for (int j = 0; j < 9; ++j) {
            float wv = wp[j];
            float pp = A6;
            pp = pp * wv + A5; pp = pp * wv + A4; pp = pp * wv + A3;
            pp = pp * wv + A2; pp = pp * wv + A1; pp = pp * wv + A0;
            float mwv = wv + gam * (pp * (s1 * wv + s0) + bo);
            mwT[(((b * 9 + j) << 7 | co) << 7) | ci] = f2bf(mwv);
        }
    }
}

// K2.5b: x -> bf16, zero-padded transpose [b][18][18][ci] (ci contiguous)
__global__ __launch_bounds__(256) void k_xt(
        const float* __restrict__ x, unsigned short* __restrict__ xT) {
    const int b = blockIdx.x, tid = threadIdx.x;
    // zero borders (68 border pixel-slots x 128 ci)
    if (tid < 68) {
        int rr, cc;
        if (tid < 18)      { rr = 0;            cc = tid; }
        else if (tid < 36) { rr = 17;           cc = tid - 18; }
        else if (tid < 52) { rr = tid - 36 + 1; cc = 0; }
        else               { rr = tid - 52 + 1; cc = 17; }
        unsigned short* dst = xT + ((size_t)b * 324 + rr * 18 + cc) * 128;
        bf16x8 z = {};
        #pragma unroll
        for (int i = 0; i < 16; ++i) *reinterpret_cast<bf16x8*>(dst + i * 8) = z;
    }
    const int py = tid >> 4, px = tid & 15;
    const float* xb = x + (size_t)b * CIN * HW + tid;
    unsigned short* dst = xT + ((size_t)b * 324 + (py + 1) * 18 + (px + 1)) * 128;
    for (int ci0 = 0; ci0 < 128; ci0 += 8) {
        bf16x8 pk;
        #pragma unroll
        for (int e = 0; e < 8; ++e) pk[e] = (short)f2bf(xb[(ci0 + e) * HW]);
        *reinterpret_cast<bf16x8*>(dst + ci0) = pk;
    }
}

// K3: shifted implicit-GEMM, MFMA bf16, no LDS. 128 blocks x 1 wave.
// wave tile: 32 co x 32 p; D[m=co][n=pixel] = sum_j sum_ci mwT * xT(shift j)
__global__ __launch_bounds__(64) void k_conv_mfma(
        const unsigned short* __restrict__ mwT,
        const unsigned short* __restrict__ xT,
        float* __restrict__ out) {
    const int wgid = blockIdx.x;          // 128 wave-tiles
    const int l = threadIdx.x;            // 0..63
    const int b = wgid >> 5;
    const int rem = wgid & 31;
    const int cobase = (rem >> 3) * 32;
    const int pbase  = (rem & 7) * 32;
    const int lr = l & 15, lk = l >> 4;

    const int p0 = pbase + lr,       p1 = pbase + 16 + lr;
    const int py0 = p0 >> 4, px0 = p0 & 15;
    const int py1 = p1 >> 4, px1 = p1 & 15;

    f32x4 acc[2][2] = {};

    #pragma unroll 1
    for (int j = 0; j < 9; ++j) {
        const int dy = j / 3, dx = j % 3;
        const unsigned short* ab = mwT + (((b * 9 + j) * 128 + cobase + lr) * 128 + lk * 8);
        const unsigned short* bb0 = xT + (((size_t)b * 324 + (py0 + dy) * 18 + (px0 + dx)) * 128 + lk * 8);
        const unsigned short* bb1 = xT + (((size_t)b * 324 + (py1 + dy) * 18 + (px1 + dx)) * 128 + lk * 8);
        #pragma unroll
        for (int c = 0; c < 4; ++c) {     // ci chunk of 32
            bf16x8 a0 = *reinterpret_cast<const bf16x8*>(ab + c * 32);
            bf16x8 a1 = *reinterpret_cast<const bf16x8*>(ab + 16 * 128 + c * 32);
            bf16x8 vb0 = *reinterpret_cast<const bf16x8*>(bb0 + c * 32);
            bf16x8 vb1 = *reinterpret_cast<const bf16x8*>(bb1 + c * 32);
            acc[0][0] = __builtin_amdgcn_mfma_f32_16x16x32_bf16(a0, vb0, acc[0][0], 0, 0, 0);
            acc[0][1] = __builtin_amdgcn_mfma_f32_16x16x32_bf16(a0, vb1, acc[0][1], 0, 0, 0);
            acc[1][0] = __builtin_amdgcn_mfma_f32_16x16x32_bf16(a1, vb0, acc[1][0], 0, 0, 0);
            acc[1][1] = __builtin_amdgcn_mfma_f32_16x16x32_bf16(a1, vb1, acc[1][1], 0, 0, 0);
        }
    }
    // C/D layout: col(n=pixel)=lane&15, row(m=co)=(lane>>4)*4+reg
    #pragma unroll
    for (int s = 0; s < 2; ++s)
        #pragma unroll
        for (int t = 0; t < 2; ++t)
            #pragma unroll
            for (int r = 0; r < 4; ++r) {
                const int co = cobase + s * 16 + lk * 4 + r;
                const int p  = pbase + t * 16 + lr;
                out[((size_t)b * COUT + co) * HW + p] = acc[s][t][r];
            }
}

extern "C" void kernel_launch(void* const* d_in, const int* in_sizes, int n_in,
                              void* d_out, int out_size, void* d_ws, size_t ws_size,
                              hipStream_t stream) {
    const float* x    = (const float*)d_in[0];
    const float* wt   = (const float*)d_in[1];
    const float* fcq  = (const float*)d_in[2];
    const float* fcqb = (const float*)d_in[3];
    const float* fck  = (const float*)d_in[4];
    // d_in[5] = fc_k_b: cancels in softmax over n -- unused
    const float* fcv  = (const float*)d_in[6];
    const float* fcvb = (const float*)d_in[7];
    const float* fco  = (const float*)d_in[8];
    const float* fcob = (const float*)d_in[9];
    const float* gam  = (const float*)d_in[10];
    float* ws  = (float*)d_ws;
    unsigned short* mwT = (unsigned short*)((char*)d_ws + MWT_OFF);
    unsigned short* xT  = (unsigned short*)((char*)d_ws + XT_OFF);
    float* out = (float*)d_out;

    hipLaunchKernelGGL(k_moments, dim3(NBLK_MOM), dim3(256), 0, stream,
                       wt, fcq, fcqb, fck, fcv, fcvb, fco, fcob, ws);
    hipLaunchKernelGGL(k_alpha, dim3(B_), dim3(1024), 0, stream, x, ws);
    hipLaunchKernelGGL(k_mask, dim3(32), dim3(256), 0, stream, wt, ws, gam, mwT);
    hipLaunchKernelGGL(k_xt, dim3(B_), dim3(256), 0, stream, x, xT);
    hipLaunchKernelGGL(k_conv_mfma, dim3(128), dim3(64), 0, stream, mwT, xT, out);
}